// Round 18
// baseline (367.161 us; speedup 1.0000x reference)
//
#include <hip/hip_runtime.h>
#include <hip/hip_fp16.h>
#include <cstdint>
#include <cstddef>

#define NEG_SLOPE 0.2f
#define HEADS 4
#define CH 64
#define HC 256   // HEADS*CH

__device__ __forceinline__ float leaky(float x) { return x > 0.f ? x : NEG_SLOPE * x; }

typedef __attribute__((ext_vector_type(8))) short short8;
typedef __attribute__((ext_vector_type(4))) float f32x4;

// round-to-nearest-even bf16 split: v ~= hi + lo, each bf16.
__device__ __forceinline__ void bf16split(float v, unsigned short& h, unsigned short& l) {
    unsigned int u = __float_as_uint(v);
    unsigned int r = u + 0x7FFF + ((u >> 16) & 1);
    h = (unsigned short)(r >> 16);
    float hf = __uint_as_float((unsigned int)h << 16);
    float lo = v - hf;
    unsigned int u2 = __float_as_uint(lo);
    unsigned int r2 = u2 + 0x7FFF + ((u2 >> 16) & 1);
    l = (unsigned short)(r2 >> 16);
}

__device__ __forceinline__ float4 half4_to_float4(uint2 u) {
    __half2 a = __builtin_bit_cast(__half2, u.x);
    __half2 b = __builtin_bit_cast(__half2, u.y);
    float2 fa = __half22float2(a);
    float2 fb = __half22float2(b);
    return make_float4(fa.x, fa.y, fb.x, fb.y);
}

// ---- one-time split of BOTH weight matrices into bf16 hi/lo, TRANSPOSED [c][K] ----
__global__ void split_b_both(const float* __restrict__ W1, const float* __restrict__ W2,
                             unsigned short* __restrict__ B1hi, unsigned short* __restrict__ B1lo,
                             unsigned short* __restrict__ B2hi, unsigned short* __restrict__ B2lo) {
    const int idx = blockIdx.x * 256 + threadIdx.x;
    unsigned short h, l;
    if (idx < 256 * 256) {                       // W1: K=256
        const int k = idx >> 8, c = idx & 255;
        bf16split(W1[idx], h, l);
        B1hi[c * 256 + k] = h;
        B1lo[c * 256 + k] = l;
    } else if (idx < 256 * 256 + 64 * 256) {     // W2: K=64
        const int i2 = idx - 256 * 256;
        const int k = i2 >> 8, c = i2 & 255;
        bf16split(W2[i2], h, l);
        B2hi[c * 64 + k] = h;
        B2lo[c * 64 + k] = l;
    }
}

// ---------------- split-bf16 MFMA GEMM + fused alpha, depth-2 on A ----------------
// C16[M x 256] = fp16(A[M x K] * B);  alpha_s/d[row][head] fused in epilogue.
// C ~= Ahi*Bhi + Ahi*Blo + Alo*Bhi. 128x128 tile, K-step 32, 4 waves (2x2 of 64x64).
// Spill forensics: round-15 = runtime-indexed set (rule #20); round-16 = arrays
// passed as const-ref PARAMETERS (address taken -> scratch). Round-12's lambda
// that only CAPTURES arrays stayed in registers. This version: two NAMED A-sets,
// each with its own capture-only lambda; zero array params, zero runtime indices.
// B depth-1 (L2-resident after first touch). K must be a multiple of 64 (256, 64 ok).
// XCD-pairing 1D grid kept (round-14: ~6us): bn-halves of one bm 8 ids apart.
#define LDP 40
__global__ __launch_bounds__(256, 3)
void gemm_mfma(const float* __restrict__ A,
               const unsigned short* __restrict__ BhiT, const unsigned short* __restrict__ BloT,
               const float* __restrict__ asrc, const float* __restrict__ adst,
               __half* __restrict__ C16, float* __restrict__ alps, float* __restrict__ alpd,
               int M, int K) {
    const int Mb = (M + 127) >> 7;
    const int id = blockIdx.x;
    const int bmi = ((id >> 4) << 3) | (id & 7);
    if (bmi >= Mb) return;
    const int bm = bmi * 128;
    const int bn = ((id >> 3) & 1) * 128;

    __shared__ unsigned short AhiS[128 * LDP];
    __shared__ unsigned short AloS[128 * LDP];
    __shared__ unsigned short BhiS[128 * LDP];
    __shared__ unsigned short BloS[128 * LDP];

    const int t  = threadIdx.x;
    const int w  = t >> 6;           // wave 0..3
    const int wr = (w >> 1) * 64;    // wave M offset
    const int wc = (w & 1) * 64;     // wave N offset
    const int lane = t & 63;
    const int l15 = lane & 15, l4 = lane >> 4;

    // staging coords
    const int ra  = t >> 3;          // A row base (0..31)
    const int ka  = (t & 7) * 4;     // A k offset
    const int cb  = t >> 1;          // B col 0..127
    const int kq  = (t & 1) * 16;    // B k offset 0/16

    float4 aP0[4], aP1[4];           // named ping-pong A prefetch sets
    uint2  bhPf[4], blPf[4];         // single B prefetch set

    auto loadA0 = [&](int kk) {
#pragma unroll
        for (int i = 0; i < 4; ++i) {
            const int gr = bm + ra + 32 * i;
            aP0[i] = (gr < M) ? *(const float4*)(A + (size_t)gr * K + kk + ka)
                              : make_float4(0.f, 0.f, 0.f, 0.f);
        }
    };
    auto loadA1 = [&](int kk) {
#pragma unroll
        for (int i = 0; i < 4; ++i) {
            const int gr = bm + ra + 32 * i;
            aP1[i] = (gr < M) ? *(const float4*)(A + (size_t)gr * K + kk + ka)
                              : make_float4(0.f, 0.f, 0.f, 0.f);
        }
    };
    auto loadB = [&](int kk) {
        const unsigned short* hs = BhiT + (size_t)(bn + cb) * K + kk + kq;
        const unsigned short* ls = BloT + (size_t)(bn + cb) * K + kk + kq;
#pragma unroll
        for (int j = 0; j < 4; ++j) {
            bhPf[j] = *(const uint2*)(hs + 4 * j);
            blPf[j] = *(const uint2*)(ls + 4 * j);
        }
    };
    auto stage0 = [&]() {
#pragma unroll
        for (int i = 0; i < 4; ++i) {
            const int row = ra + 32 * i;
            unsigned short h0, h1, h2, h3, l0, l1, l2, l3;
            bf16split(aP0[i].x, h0, l0); bf16split(aP0[i].y, h1, l1);
            bf16split(aP0[i].z, h2, l2); bf16split(aP0[i].w, h3, l3);
            uint2 hp, lp;
            hp.x = (unsigned int)h0 | ((unsigned int)h1 << 16);
            hp.y = (unsigned int)h2 | ((unsigned int)h3 << 16);
            lp.x = (unsigned int)l0 | ((unsigned int)l1 << 16);
            lp.y = (unsigned int)l2 | ((unsigned int)l3 << 16);
            *(uint2*)&AhiS[row * LDP + ka] = hp;
            *(uint2*)&AloS[row * LDP + ka] = lp;
        }
    };
    auto stage1 = [&]() {
#pragma unroll
        for (int i = 0; i < 4; ++i) {
            const int row = ra + 32 * i;
            unsigned short h0, h1, h2, h3, l0, l1, l2, l3;
            bf16split(aP1[i].x, h0, l0); bf16split(aP1[i].y, h1, l1);
            bf16split(aP1[i].z, h2, l2); bf16split(aP1[i].w, h3, l3);
            uint2 hp, lp;
            hp.x = (unsigned int)h0 | ((unsigned int)h1 << 16);
            hp.y = (unsigned int)h2 | ((unsigned int)h3 << 16);
            lp.x = (unsigned int)l0 | ((unsigned int)l1 << 16);
            lp.y = (unsigned int)l2 | ((unsigned int)l3 << 16);
            *(uint2*)&AhiS[row * LDP + ka] = hp;
            *(uint2*)&AloS[row * LDP + ka] = lp;
        }
    };
    auto stageB = [&]() {
#pragma unroll
        for (int j = 0; j < 4; ++j) {
            *(uint2*)&BhiS[cb * LDP + kq + 4 * j] = bhPf[j];
            *(uint2*)&BloS[cb * LDP + kq + 4 * j] = blPf[j];
        }
    };

    f32x4 acc[4][4];
#pragma unroll
    for (int i = 0; i < 4; ++i)
#pragma unroll
        for (int j = 0; j < 4; ++j) acc[i][j] = (f32x4)0.f;

    auto compute = [&]() {
        short8 ah[4], al[4], bh[4], bl[4];
#pragma unroll
        for (int s = 0; s < 4; ++s) {
            ah[s] = *(const short8*)&AhiS[(wr + s * 16 + l15) * LDP + l4 * 8];
            al[s] = *(const short8*)&AloS[(wr + s * 16 + l15) * LDP + l4 * 8];
            bh[s] = *(const short8*)&BhiS[(wc + s * 16 + l15) * LDP + l4 * 8];
            bl[s] = *(const short8*)&BloS[(wc + s * 16 + l15) * LDP + l4 * 8];
        }
#pragma unroll
        for (int ms = 0; ms < 4; ++ms)
#pragma unroll
            for (int cs = 0; cs < 4; ++cs) {
                acc[ms][cs] = __builtin_amdgcn_mfma_f32_16x16x32_bf16(ah[ms], bh[cs], acc[ms][cs], 0, 0, 0);
                acc[ms][cs] = __builtin_amdgcn_mfma_f32_16x16x32_bf16(ah[ms], bl[cs], acc[ms][cs], 0, 0, 0);
                acc[ms][cs] = __builtin_amdgcn_mfma_f32_16x16x32_bf16(al[ms], bh[cs], acc[ms][cs], 0, 0, 0);
            }
    };

    // prologue: A depth-2, B depth-1
    loadA0(0);
    loadB(0);
    if (K > 32) loadA1(32);

    for (int k0 = 0; k0 < K; k0 += 64) {
        // ---- phase A: consume tile k0 (from aP0) ----
        stage0();
        stageB();
        __syncthreads();
        if (k0 + 64 < K) loadA0(k0 + 64);   // refill aP0, used 2 phases later
        loadB(k0 + 32);                     // next step's B (L2-hit)
        compute();
        __syncthreads();

        // ---- phase B: consume tile k0+32 (from aP1) ----
        stage1();
        stageB();
        __syncthreads();
        if (k0 + 96 < K) loadA1(k0 + 96);   // refill aP1, used 2 phases later
        if (k0 + 64 < K) loadB(k0 + 64);    // next iteration's B
        compute();
        __syncthreads();
    }

    // ---- epilogue: D col = lane&15, row = (lane>>4)*4 + reg ----
#pragma unroll
    for (int ms = 0; ms < 4; ++ms) {
        const int gr0 = bm + wr + ms * 16 + l4 * 4;
#pragma unroll
        for (int cs = 0; cs < 4; ++cs) {
            const int gc = bn + wc + cs * 16 + l15;
            const f32x4 d = acc[ms][cs];
#pragma unroll
            for (int r = 0; r < 4; ++r) {
                if (gr0 + r < M) C16[(size_t)(gr0 + r) * HC + gc] = __float2half_rn(d[r]);
            }
        }
    }

    // ---- fused alpha: this wave's 64 cols = head hd0 ----
    const int hd0 = (bn + wc) >> 6;
    float asv[4], adv[4];
#pragma unroll
    for (int cs = 0; cs < 4; ++cs) {
        const int gc = bn + wc + cs * 16 + l15;   // flat [H][C] index == column index
        asv[cs] = asrc[gc];
        adv[cs] = adst[gc];
    }
#pragma unroll
    for (int ms = 0; ms < 4; ++ms) {
        float ps[4] = {0.f, 0.f, 0.f, 0.f};
        float pd[4] = {0.f, 0.f, 0.f, 0.f};
#pragma unroll
        for (int cs = 0; cs < 4; ++cs) {
            const f32x4 d = acc[ms][cs];
#pragma unroll
            for (int r = 0; r < 4; ++r) {
                ps[r] += d[r] * asv[cs];
                pd[r] += d[r] * adv[cs];
            }
        }
#pragma unroll
        for (int m = 1; m <= 8; m <<= 1) {
#pragma unroll
            for (int r = 0; r < 4; ++r) {
                ps[r] += __shfl_xor(ps[r], m);
                pd[r] += __shfl_xor(pd[r], m);
            }
        }
        if (l15 == 0) {
            const int row0 = bm + wr + ms * 16 + l4 * 4;
#pragma unroll
            for (int r = 0; r < 4; ++r) {
                if (row0 + r < M) {
                    alps[(row0 + r) * 4 + hd0] = ps[r];
                    alpd[(row0 + r) * 4 + hd0] = pd[r];
                }
            }
        }
    }
}

// ================= CSR construction (once per call; graph shared by both layers) =================
__global__ void hist_kernel(const int* __restrict__ ei, int* __restrict__ cnt, int E) {
    const int e = blockIdx.x * 256 + threadIdx.x;
    if (e >= E) return;
    atomicAdd(&cnt[ei[E + e]], 1);
}

__global__ void scan1_kernel(const int* __restrict__ cnt, int* __restrict__ excl,
                             int* __restrict__ bsum, int n) {
    __shared__ int tmp[256];
    const int tid = threadIdx.x;
    const int gid = blockIdx.x * 256 + tid;
    const int v = (gid < n) ? cnt[gid] : 0;
    tmp[tid] = v;
    __syncthreads();
    for (int off = 1; off < 256; off <<= 1) {
        const int t = (tid >= off) ? tmp[tid - off] : 0;
        __syncthreads();
        tmp[tid] += t;
        __syncthreads();
    }
    if (gid < n) excl[gid] = tmp[tid] - v;
    if (tid == 255) bsum[blockIdx.x] = tmp[255];
}

__global__ void scan2_kernel(int* __restrict__ bsum, int nb) {
    __shared__ int tmp[256];
    const int tid = threadIdx.x;
    const int v = (tid < nb) ? bsum[tid] : 0;
    tmp[tid] = v;
    __syncthreads();
    for (int off = 1; off < 256; off <<= 1) {
        const int t = (tid >= off) ? tmp[tid - off] : 0;
        __syncthreads();
        tmp[tid] += t;
        __syncthreads();
    }
    if (tid < nb) bsum[tid] = tmp[tid] - v;
}

__global__ void scan3_kernel(const int* __restrict__ excl, const int* __restrict__ bsum,
                             int* __restrict__ row_ptr, int* __restrict__ woff, int n) {
    const int gid = blockIdx.x * 256 + threadIdx.x;
    if (gid >= n) return;
    const int v = excl[gid] + bsum[blockIdx.x];
    row_ptr[gid] = v;
    woff[gid] = v;
}

__global__ void scatter_kernel(const int* __restrict__ ei, int* __restrict__ woff,
                               int* __restrict__ ssrc, int E) {
    const int e = blockIdx.x * 256 + threadIdx.x;
    if (e >= E) return;
    const int pos = atomicAdd(&woff[ei[E + e]], 1);
    ssrc[pos] = ei[e];
}

// ================= fused GAT aggregation: one wave per dst node (round-12 PROVEN form) ======
// round-6 lesson: single-address atomic work counter serializes across XCDs.
// round-9 lesson: intra-wave relayout of the gather path is neutral.
// round-13 lesson: shfl-broadcast batching destroys MLP (66->99us).
// round-14 lesson: 16-deep batch trades TLP for ILP at a net loss; 8 is the knee.
// Head-per-lane-group: lane = head*16 + chgrp; one exp + one 8B fp16 load per edge per lane.
template<int U>
__device__ __forceinline__ void gat_batch16(int e, const int* __restrict__ ssrc,
                                            const float* __restrict__ alps,
                                            const __half* __restrict__ h16, int hoff, int hd,
                                            float aDh, float4& acc, float& den) {
    int s[U];
#pragma unroll
    for (int u = 0; u < U; ++u) s[u] = ssrc[e + u];
    float aS[U];
#pragma unroll
    for (int u = 0; u < U; ++u) aS[u] = alps[s[u] * 4 + hd];
    uint2 hv[U];
#pragma unroll
    for (int u = 0; u < U; ++u) hv[u] = *(const uint2*)(h16 + (size_t)s[u] * HC + hoff);
#pragma unroll
    for (int u = 0; u < U; ++u) {
        const float w = __expf(leaky(aS[u] + aDh));
        const float4 f = half4_to_float4(hv[u]);
        acc.x += w * f.x; acc.y += w * f.y;
        acc.z += w * f.z; acc.w += w * f.w;
        den += w;
    }
}

__global__ __launch_bounds__(256)
void agg_csr_kernel(const int* __restrict__ row_ptr, const int* __restrict__ cnt,
                    const int* __restrict__ ssrc,
                    const float* __restrict__ alps, const float* __restrict__ alpd,
                    const __half* __restrict__ h16, const float* __restrict__ bias,
                    float* __restrict__ outp, int Nn, int do_elu) {
    const int n = blockIdx.x * 4 + (threadIdx.x >> 6);
    const int lane = threadIdx.x & 63;
    const int hd = lane >> 4;        // head
    const int g  = lane & 15;        // channel group (4 ch)
    const int hoff = hd * CH + g * 4;
    if (n >= Nn) return;

    const float aDh = alpd[n * 4 + hd];
    float4 acc;
    float den;
    {   // self-loop
        const float w = __expf(leaky(alps[n * 4 + hd] + aDh));
        const float4 f = half4_to_float4(*(const uint2*)(h16 + (size_t)n * HC + hoff));
        acc.x = w * f.x; acc.y = w * f.y; acc.z = w * f.z; acc.w = w * f.w;
        den = w;
    }

    const int beg = row_ptr[n];
    const int end = beg + cnt[n];
    int e = beg;
    for (; e + 8 <= end; e += 8) gat_batch16<8>(e, ssrc, alps, h16, hoff, hd, aDh, acc, den);
    for (; e + 4 <= end; e += 4) gat_batch16<4>(e, ssrc, alps, h16, hoff, hd, aDh, acc, den);
    for (; e < end; ++e)         gat_batch16<1>(e, ssrc, alps, h16, hoff, hd, aDh, acc, den);

    // normalize this head, then butterfly-sum over heads (lanes g, g+16, g+32, g+48)
    float4 v;
    const float r = 1.f / den;
    v.x = acc.x * r; v.y = acc.y * r; v.z = acc.z * r; v.w = acc.w * r;
#pragma unroll
    for (int m = 16; m <= 32; m <<= 1) {
        v.x += __shfl_xor(v.x, m);
        v.y += __shfl_xor(v.y, m);
        v.z += __shfl_xor(v.z, m);
        v.w += __shfl_xor(v.w, m);
    }
    if (hd == 0) {
        const float4 b4 = *(const float4*)&bias[g * 4];
        v.x = 0.25f * v.x + b4.x;
        v.y = 0.25f * v.y + b4.y;
        v.z = 0.25f * v.z + b4.z;
        v.w = 0.25f * v.w + b4.w;
        if (do_elu) {
            v.x = v.x > 0.f ? v.x : expm1f(v.x);
            v.y = v.y > 0.f ? v.y : expm1f(v.y);
            v.z = v.z > 0.f ? v.z : expm1f(v.z);
            v.w = v.w > 0.f ? v.w : expm1f(v.w);
        }
        *(float4*)&outp[(size_t)n * CH + g * 4] = v;
    }
}

// ------------------------------------------------------------------
extern "C" void kernel_launch(void* const* d_in, const int* in_sizes, int n_in,
                              void* d_out, int out_size, void* d_ws, size_t ws_size,
                              hipStream_t stream) {
    const float* x   = (const float*)d_in[0];
    const int*   ei  = (const int*)d_in[1];
    const float* W1  = (const float*)d_in[2];
    const float* a1s = (const float*)d_in[3];
    const float* a1d = (const float*)d_in[4];
    const float* b1  = (const float*)d_in[5];
    const float* W2  = (const float*)d_in[6];
    const float* a2s = (const float*)d_in[7];
    const float* a2d = (const float*)d_in[8];
    const float* b2  = (const float*)d_in[9];

    const int N = in_sizes[0] / HC;   // 50000
    const int E = in_sizes[1] / 2;    // 800000

    char* ws = (char*)d_ws;
    size_t off = 0;
    __half* h16    = (__half*)(ws + off);        off += (size_t)N * HC * 2;
    float* alps    = (float*)(ws + off);         off += (size_t)N * HEADS * 4;
    float* alpd    = (float*)(ws + off);         off += (size_t)N * HEADS * 4;
    int*   cnt     = (int*)(ws + off);           off += (size_t)N * 4;
    int*   excl    = (int*)(ws + off);           off += (size_t)N * 4;
    int*   row_ptr = (int*)(ws + off);           off += (size_t)N * 4;
    int*   woff    = (int*)(ws + off);           off += (size_t)N * 4;
    int*   bsum    = (int*)(ws + off);           off += 256 * 4;
    int*   ssrc    = (int*)(ws + off);           off += (size_t)E * 4;
    unsigned short* B1hi = (unsigned short*)(ws + off); off += 256 * 256 * 2;
    unsigned short* B1lo = (unsigned short*)(ws + off); off += 256 * 256 * 2;
    unsigned short* B2hi = (unsigned short*)(ws + off); off += 64 * 256 * 2;
    unsigned short* B2lo = (unsigned short*)(ws + off); off += 64 * 256 * 2;
    float* outp    = (float*)d_out;

    const int eb   = (E + 255) / 256;
    const int nb   = (N + 255) / 256;        // 196 <= 256 (scan2 single-block limit)
    const int n4b  = (N + 3) / 4;
    const int Mb   = (N + 127) / 128;        // 391
    const int gemm_blocks = ((Mb + 7) / 8) * 16;   // padded XCD-paired 1D grid (784)

    // ---- weight pre-split (both layers, one launch) + CSR build ----
    split_b_both<<<(256 * 256 + 64 * 256 + 255) / 256, 256, 0, stream>>>(W1, W2, B1hi, B1lo, B2hi, B2lo);
    hipMemsetAsync(cnt, 0, (size_t)N * 4, stream);
    hist_kernel<<<eb, 256, 0, stream>>>(ei, cnt, E);
    scan1_kernel<<<nb, 256, 0, stream>>>(cnt, excl, bsum, N);
    scan2_kernel<<<1, 256, 0, stream>>>(bsum, nb);
    scan3_kernel<<<nb, 256, 0, stream>>>(excl, bsum, row_ptr, woff, N);
    scatter_kernel<<<eb, 256, 0, stream>>>(ei, woff, ssrc, E);

    // ---------------- layer 1 (gemm + fused alpha) ----------------
    gemm_mfma<<<gemm_blocks, 256, 0, stream>>>(x, B1hi, B1lo, a1s, a1d,
                                               h16, alps, alpd, N, 256);
    agg_csr_kernel<<<n4b, 256, 0, stream>>>(row_ptr, cnt, ssrc, alps, alpd,
                                            h16, b1, outp, N, 1);

    // ---------------- layer 2 (gemm + fused alpha) ----------------
    gemm_mfma<<<gemm_blocks, 256, 0, stream>>>(outp, B2hi, B2lo, a2s, a2d,
                                               h16, alps, alpd, N, 64);
    agg_csr_kernel<<<n4b, 256, 0, stream>>>(row_ptr, cnt, ssrc, alps, alpd,
                                            h16, b2, outp, N, 0);
}

// Round 19
// 301.882 us; speedup vs baseline: 1.2162x; 1.2162x over previous
//
#include <hip/hip_runtime.h>
#include <hip/hip_fp16.h>
#include <cstdint>
#include <cstddef>

#define NEG_SLOPE 0.2f
#define HEADS 4
#define CH 64
#define HC 256   // HEADS*CH

__device__ __forceinline__ float leaky(float x) { return x > 0.f ? x : NEG_SLOPE * x; }

typedef __attribute__((ext_vector_type(8))) short short8;
typedef __attribute__((ext_vector_type(4))) float f32x4;

// round-to-nearest-even bf16 split: v ~= hi + lo, each bf16.
__device__ __forceinline__ void bf16split(float v, unsigned short& h, unsigned short& l) {
    unsigned int u = __float_as_uint(v);
    unsigned int r = u + 0x7FFF + ((u >> 16) & 1);
    h = (unsigned short)(r >> 16);
    float hf = __uint_as_float((unsigned int)h << 16);
    float lo = v - hf;
    unsigned int u2 = __float_as_uint(lo);
    unsigned int r2 = u2 + 0x7FFF + ((u2 >> 16) & 1);
    l = (unsigned short)(r2 >> 16);
}

__device__ __forceinline__ float4 half4_to_float4(uint2 u) {
    __half2 a = __builtin_bit_cast(__half2, u.x);
    __half2 b = __builtin_bit_cast(__half2, u.y);
    float2 fa = __half22float2(a);
    float2 fb = __half22float2(b);
    return make_float4(fa.x, fa.y, fb.x, fb.y);
}

// ---- one-time split of BOTH weight matrices into bf16 hi/lo, TRANSPOSED [c][K] ----
__global__ void split_b_both(const float* __restrict__ W1, const float* __restrict__ W2,
                             unsigned short* __restrict__ B1hi, unsigned short* __restrict__ B1lo,
                             unsigned short* __restrict__ B2hi, unsigned short* __restrict__ B2lo) {
    const int idx = blockIdx.x * 256 + threadIdx.x;
    unsigned short h, l;
    if (idx < 256 * 256) {                       // W1: K=256
        const int k = idx >> 8, c = idx & 255;
        bf16split(W1[idx], h, l);
        B1hi[c * 256 + k] = h;
        B1lo[c * 256 + k] = l;
    } else if (idx < 256 * 256 + 64 * 256) {     // W2: K=64
        const int i2 = idx - 256 * 256;
        const int k = i2 >> 8, c = i2 & 255;
        bf16split(W2[i2], h, l);
        B2hi[c * 64 + k] = h;
        B2lo[c * 64 + k] = l;
    }
}

// ---------------- split-bf16 MFMA GEMM + fused alpha, depth-1 pipelined ----------------
// C16[M x 256] = fp16(A[M x K] * B);  alpha_s/d[row][head] fused in epilogue.
// C ~= Ahi*Bhi + Ahi*Blo + Alo*Bhi. 128x128 tile, K-step 32, 4 waves (2x2 of 64x64).
// FINAL FORM (round-12 body + round-14 XCD-paired grid). Depth-2 prefetch is dead:
// rounds 15/16/18 all spilled to scratch (94-224MB extra traffic) regardless of
// source form -- 2 live prefetch sets + 64-VGPR acc across two barriers exceeds
// what the allocator will hold. The path past this is the 8-phase restructure
// (out of scope). XCD-pairing: bn-halves of one bm land 8 ids apart -> same XCD
// -> A panel L2-shared (~6us on the gemm pair, round-14).
#define LDP 40
__global__ __launch_bounds__(256, 3)
void gemm_mfma(const float* __restrict__ A,
               const unsigned short* __restrict__ BhiT, const unsigned short* __restrict__ BloT,
               const float* __restrict__ asrc, const float* __restrict__ adst,
               __half* __restrict__ C16, float* __restrict__ alps, float* __restrict__ alpd,
               int M, int K) {
    const int Mb = (M + 127) >> 7;
    const int id = blockIdx.x;
    const int bmi = ((id >> 4) << 3) | (id & 7);
    if (bmi >= Mb) return;
    const int bm = bmi * 128;
    const int bn = ((id >> 3) & 1) * 128;

    __shared__ unsigned short AhiS[128 * LDP];
    __shared__ unsigned short AloS[128 * LDP];
    __shared__ unsigned short BhiS[128 * LDP];
    __shared__ unsigned short BloS[128 * LDP];

    const int t  = threadIdx.x;
    const int w  = t >> 6;           // wave 0..3
    const int wr = (w >> 1) * 64;    // wave M offset
    const int wc = (w & 1) * 64;     // wave N offset
    const int lane = t & 63;
    const int l15 = lane & 15, l4 = lane >> 4;

    // staging coords
    const int ra  = t >> 3;          // A row base (0..31)
    const int ka  = (t & 7) * 4;     // A k offset
    const int cb  = t >> 1;          // B col 0..127
    const int kq  = (t & 1) * 16;    // B k offset 0/16

    float4 aPf[4];
    uint2  bhPf[4], blPf[4];

    auto load_tiles = [&](int kk) {
#pragma unroll
        for (int i = 0; i < 4; ++i) {
            const int gr = bm + ra + 32 * i;
            aPf[i] = (gr < M) ? *(const float4*)(A + (size_t)gr * K + kk + ka)
                              : make_float4(0.f, 0.f, 0.f, 0.f);
        }
        const unsigned short* hs = BhiT + (size_t)(bn + cb) * K + kk + kq;
        const unsigned short* ls = BloT + (size_t)(bn + cb) * K + kk + kq;
#pragma unroll
        for (int j = 0; j < 4; ++j) {
            bhPf[j] = *(const uint2*)(hs + 4 * j);
            blPf[j] = *(const uint2*)(ls + 4 * j);
        }
    };

    f32x4 acc[4][4];
#pragma unroll
    for (int i = 0; i < 4; ++i)
#pragma unroll
        for (int j = 0; j < 4; ++j) acc[i][j] = (f32x4)0.f;

    load_tiles(0);   // prologue prefetch

    for (int k0 = 0; k0 < K; k0 += 32) {
        // ---- write prefetched tile to LDS (A split in-flight; round-10 lesson:
        //      separate pre-split pass costs more stream traffic than this VALU) ----
#pragma unroll
        for (int i = 0; i < 4; ++i) {
            const int row = ra + 32 * i;
            unsigned short h0, h1, h2, h3, l0, l1, l2, l3;
            bf16split(aPf[i].x, h0, l0); bf16split(aPf[i].y, h1, l1);
            bf16split(aPf[i].z, h2, l2); bf16split(aPf[i].w, h3, l3);
            uint2 hp, lp;
            hp.x = (unsigned int)h0 | ((unsigned int)h1 << 16);
            hp.y = (unsigned int)h2 | ((unsigned int)h3 << 16);
            lp.x = (unsigned int)l0 | ((unsigned int)l1 << 16);
            lp.y = (unsigned int)l2 | ((unsigned int)l3 << 16);
            *(uint2*)&AhiS[row * LDP + ka] = hp;
            *(uint2*)&AloS[row * LDP + ka] = lp;
        }
#pragma unroll
        for (int j = 0; j < 4; ++j) {
            *(uint2*)&BhiS[cb * LDP + kq + 4 * j] = bhPf[j];
            *(uint2*)&BloS[cb * LDP + kq + 4 * j] = blPf[j];
        }
        __syncthreads();

        if (k0 + 32 < K) load_tiles(k0 + 32);   // next tile flies during MFMA below

        // ---- fragments: lane&15 = row (A) / col (B^T), lane>>4 = k-octet ----
        short8 ah[4], al[4], bh[4], bl[4];
#pragma unroll
        for (int s = 0; s < 4; ++s) {
            ah[s] = *(const short8*)&AhiS[(wr + s * 16 + l15) * LDP + l4 * 8];
            al[s] = *(const short8*)&AloS[(wr + s * 16 + l15) * LDP + l4 * 8];
            bh[s] = *(const short8*)&BhiS[(wc + s * 16 + l15) * LDP + l4 * 8];
            bl[s] = *(const short8*)&BloS[(wc + s * 16 + l15) * LDP + l4 * 8];
        }
#pragma unroll
        for (int ms = 0; ms < 4; ++ms)
#pragma unroll
            for (int cs = 0; cs < 4; ++cs) {
                acc[ms][cs] = __builtin_amdgcn_mfma_f32_16x16x32_bf16(ah[ms], bh[cs], acc[ms][cs], 0, 0, 0);
                acc[ms][cs] = __builtin_amdgcn_mfma_f32_16x16x32_bf16(ah[ms], bl[cs], acc[ms][cs], 0, 0, 0);
                acc[ms][cs] = __builtin_amdgcn_mfma_f32_16x16x32_bf16(al[ms], bh[cs], acc[ms][cs], 0, 0, 0);
            }
        __syncthreads();
    }

    // ---- epilogue: D col = lane&15, row = (lane>>4)*4 + reg ----
#pragma unroll
    for (int ms = 0; ms < 4; ++ms) {
        const int gr0 = bm + wr + ms * 16 + l4 * 4;
#pragma unroll
        for (int cs = 0; cs < 4; ++cs) {
            const int gc = bn + wc + cs * 16 + l15;
            const f32x4 d = acc[ms][cs];
#pragma unroll
            for (int r = 0; r < 4; ++r) {
                if (gr0 + r < M) C16[(size_t)(gr0 + r) * HC + gc] = __float2half_rn(d[r]);
            }
        }
    }

    // ---- fused alpha: this wave's 64 cols = head hd0 ----
    const int hd0 = (bn + wc) >> 6;
    float asv[4], adv[4];
#pragma unroll
    for (int cs = 0; cs < 4; ++cs) {
        const int gc = bn + wc + cs * 16 + l15;   // flat [H][C] index == column index
        asv[cs] = asrc[gc];
        adv[cs] = adst[gc];
    }
#pragma unroll
    for (int ms = 0; ms < 4; ++ms) {
        float ps[4] = {0.f, 0.f, 0.f, 0.f};
        float pd[4] = {0.f, 0.f, 0.f, 0.f};
#pragma unroll
        for (int cs = 0; cs < 4; ++cs) {
            const f32x4 d = acc[ms][cs];
#pragma unroll
            for (int r = 0; r < 4; ++r) {
                ps[r] += d[r] * asv[cs];
                pd[r] += d[r] * adv[cs];
            }
        }
#pragma unroll
        for (int m = 1; m <= 8; m <<= 1) {
#pragma unroll
            for (int r = 0; r < 4; ++r) {
                ps[r] += __shfl_xor(ps[r], m);
                pd[r] += __shfl_xor(pd[r], m);
            }
        }
        if (l15 == 0) {
            const int row0 = bm + wr + ms * 16 + l4 * 4;
#pragma unroll
            for (int r = 0; r < 4; ++r) {
                if (row0 + r < M) {
                    alps[(row0 + r) * 4 + hd0] = ps[r];
                    alpd[(row0 + r) * 4 + hd0] = pd[r];
                }
            }
        }
    }
}

// ================= CSR construction (once per call; graph shared by both layers) =================
__global__ void hist_kernel(const int* __restrict__ ei, int* __restrict__ cnt, int E) {
    const int e = blockIdx.x * 256 + threadIdx.x;
    if (e >= E) return;
    atomicAdd(&cnt[ei[E + e]], 1);
}

__global__ void scan1_kernel(const int* __restrict__ cnt, int* __restrict__ excl,
                             int* __restrict__ bsum, int n) {
    __shared__ int tmp[256];
    const int tid = threadIdx.x;
    const int gid = blockIdx.x * 256 + tid;
    const int v = (gid < n) ? cnt[gid] : 0;
    tmp[tid] = v;
    __syncthreads();
    for (int off = 1; off < 256; off <<= 1) {
        const int t = (tid >= off) ? tmp[tid - off] : 0;
        __syncthreads();
        tmp[tid] += t;
        __syncthreads();
    }
    if (gid < n) excl[gid] = tmp[tid] - v;
    if (tid == 255) bsum[blockIdx.x] = tmp[255];
}

__global__ void scan2_kernel(int* __restrict__ bsum, int nb) {
    __shared__ int tmp[256];
    const int tid = threadIdx.x;
    const int v = (tid < nb) ? bsum[tid] : 0;
    tmp[tid] = v;
    __syncthreads();
    for (int off = 1; off < 256; off <<= 1) {
        const int t = (tid >= off) ? tmp[tid - off] : 0;
        __syncthreads();
        tmp[tid] += t;
        __syncthreads();
    }
    if (tid < nb) bsum[tid] = tmp[tid] - v;
}

__global__ void scan3_kernel(const int* __restrict__ excl, const int* __restrict__ bsum,
                             int* __restrict__ row_ptr, int* __restrict__ woff, int n) {
    const int gid = blockIdx.x * 256 + threadIdx.x;
    if (gid >= n) return;
    const int v = excl[gid] + bsum[blockIdx.x];
    row_ptr[gid] = v;
    woff[gid] = v;
}

__global__ void scatter_kernel(const int* __restrict__ ei, int* __restrict__ woff,
                               int* __restrict__ ssrc, int E) {
    const int e = blockIdx.x * 256 + threadIdx.x;
    if (e >= E) return;
    const int pos = atomicAdd(&woff[ei[E + e]], 1);
    ssrc[pos] = ei[e];
}

// ================= fused GAT aggregation: one wave per dst node (PROVEN form) ======
// round-6 lesson: single-address atomic work counter serializes across XCDs.
// round-9 lesson: intra-wave relayout of the gather path is neutral.
// round-13 lesson: shfl-broadcast batching destroys MLP (66->99us).
// round-14 lesson: 16-deep batch trades TLP for ILP at a net loss; 8 is the knee.
// Head-per-lane-group: lane = head*16 + chgrp; one exp + one 8B fp16 load per edge per lane.
template<int U>
__device__ __forceinline__ void gat_batch16(int e, const int* __restrict__ ssrc,
                                            const float* __restrict__ alps,
                                            const __half* __restrict__ h16, int hoff, int hd,
                                            float aDh, float4& acc, float& den) {
    int s[U];
#pragma unroll
    for (int u = 0; u < U; ++u) s[u] = ssrc[e + u];
    float aS[U];
#pragma unroll
    for (int u = 0; u < U; ++u) aS[u] = alps[s[u] * 4 + hd];
    uint2 hv[U];
#pragma unroll
    for (int u = 0; u < U; ++u) hv[u] = *(const uint2*)(h16 + (size_t)s[u] * HC + hoff);
#pragma unroll
    for (int u = 0; u < U; ++u) {
        const float w = __expf(leaky(aS[u] + aDh));
        const float4 f = half4_to_float4(hv[u]);
        acc.x += w * f.x; acc.y += w * f.y;
        acc.z += w * f.z; acc.w += w * f.w;
        den += w;
    }
}

__global__ __launch_bounds__(256)
void agg_csr_kernel(const int* __restrict__ row_ptr, const int* __restrict__ cnt,
                    const int* __restrict__ ssrc,
                    const float* __restrict__ alps, const float* __restrict__ alpd,
                    const __half* __restrict__ h16, const float* __restrict__ bias,
                    float* __restrict__ outp, int Nn, int do_elu) {
    const int n = blockIdx.x * 4 + (threadIdx.x >> 6);
    const int lane = threadIdx.x & 63;
    const int hd = lane >> 4;        // head
    const int g  = lane & 15;        // channel group (4 ch)
    const int hoff = hd * CH + g * 4;
    if (n >= Nn) return;

    const float aDh = alpd[n * 4 + hd];
    float4 acc;
    float den;
    {   // self-loop
        const float w = __expf(leaky(alps[n * 4 + hd] + aDh));
        const float4 f = half4_to_float4(*(const uint2*)(h16 + (size_t)n * HC + hoff));
        acc.x = w * f.x; acc.y = w * f.y; acc.z = w * f.z; acc.w = w * f.w;
        den = w;
    }

    const int beg = row_ptr[n];
    const int end = beg + cnt[n];
    int e = beg;
    for (; e + 8 <= end; e += 8) gat_batch16<8>(e, ssrc, alps, h16, hoff, hd, aDh, acc, den);
    for (; e + 4 <= end; e += 4) gat_batch16<4>(e, ssrc, alps, h16, hoff, hd, aDh, acc, den);
    for (; e < end; ++e)         gat_batch16<1>(e, ssrc, alps, h16, hoff, hd, aDh, acc, den);

    // normalize this head, then butterfly-sum over heads (lanes g, g+16, g+32, g+48)
    float4 v;
    const float r = 1.f / den;
    v.x = acc.x * r; v.y = acc.y * r; v.z = acc.z * r; v.w = acc.w * r;
#pragma unroll
    for (int m = 16; m <= 32; m <<= 1) {
        v.x += __shfl_xor(v.x, m);
        v.y += __shfl_xor(v.y, m);
        v.z += __shfl_xor(v.z, m);
        v.w += __shfl_xor(v.w, m);
    }
    if (hd == 0) {
        const float4 b4 = *(const float4*)&bias[g * 4];
        v.x = 0.25f * v.x + b4.x;
        v.y = 0.25f * v.y + b4.y;
        v.z = 0.25f * v.z + b4.z;
        v.w = 0.25f * v.w + b4.w;
        if (do_elu) {
            v.x = v.x > 0.f ? v.x : expm1f(v.x);
            v.y = v.y > 0.f ? v.y : expm1f(v.y);
            v.z = v.z > 0.f ? v.z : expm1f(v.z);
            v.w = v.w > 0.f ? v.w : expm1f(v.w);
        }
        *(float4*)&outp[(size_t)n * CH + g * 4] = v;
    }
}

// ------------------------------------------------------------------
extern "C" void kernel_launch(void* const* d_in, const int* in_sizes, int n_in,
                              void* d_out, int out_size, void* d_ws, size_t ws_size,
                              hipStream_t stream) {
    const float* x   = (const float*)d_in[0];
    const int*   ei  = (const int*)d_in[1];
    const float* W1  = (const float*)d_in[2];
    const float* a1s = (const float*)d_in[3];
    const float* a1d = (const float*)d_in[4];
    const float* b1  = (const float*)d_in[5];
    const float* W2  = (const float*)d_in[6];
    const float* a2s = (const float*)d_in[7];
    const float* a2d = (const float*)d_in[8];
    const float* b2  = (const float*)d_in[9];

    const int N = in_sizes[0] / HC;   // 50000
    const int E = in_sizes[1] / 2;    // 800000

    char* ws = (char*)d_ws;
    size_t off = 0;
    __half* h16    = (__half*)(ws + off);        off += (size_t)N * HC * 2;
    float* alps    = (float*)(ws + off);         off += (size_t)N * HEADS * 4;
    float* alpd    = (float*)(ws + off);         off += (size_t)N * HEADS * 4;
    int*   cnt     = (int*)(ws + off);           off += (size_t)N * 4;
    int*   excl    = (int*)(ws + off);           off += (size_t)N * 4;
    int*   row_ptr = (int*)(ws + off);           off += (size_t)N * 4;
    int*   woff    = (int*)(ws + off);           off += (size_t)N * 4;
    int*   bsum    = (int*)(ws + off);           off += 256 * 4;
    int*   ssrc    = (int*)(ws + off);           off += (size_t)E * 4;
    unsigned short* B1hi = (unsigned short*)(ws + off); off += 256 * 256 * 2;
    unsigned short* B1lo = (unsigned short*)(ws + off); off += 256 * 256 * 2;
    unsigned short* B2hi = (unsigned short*)(ws + off); off += 64 * 256 * 2;
    unsigned short* B2lo = (unsigned short*)(ws + off); off += 64 * 256 * 2;
    float* outp    = (float*)d_out;

    const int eb   = (E + 255) / 256;
    const int nb   = (N + 255) / 256;        // 196 <= 256 (scan2 single-block limit)
    const int n4b  = (N + 3) / 4;
    const int Mb   = (N + 127) / 128;        // 391
    const int gemm_blocks = ((Mb + 7) / 8) * 16;   // padded XCD-paired 1D grid (784)

    // ---- weight pre-split (both layers, one launch) + CSR build ----
    split_b_both<<<(256 * 256 + 64 * 256 + 255) / 256, 256, 0, stream>>>(W1, W2, B1hi, B1lo, B2hi, B2lo);
    hipMemsetAsync(cnt, 0, (size_t)N * 4, stream);
    hist_kernel<<<eb, 256, 0, stream>>>(ei, cnt, E);
    scan1_kernel<<<nb, 256, 0, stream>>>(cnt, excl, bsum, N);
    scan2_kernel<<<1, 256, 0, stream>>>(bsum, nb);
    scan3_kernel<<<nb, 256, 0, stream>>>(excl, bsum, row_ptr, woff, N);
    scatter_kernel<<<eb, 256, 0, stream>>>(ei, woff, ssrc, E);

    // ---------------- layer 1 (gemm + fused alpha) ----------------
    gemm_mfma<<<gemm_blocks, 256, 0, stream>>>(x, B1hi, B1lo, a1s, a1d,
                                               h16, alps, alpd, N, 256);
    agg_csr_kernel<<<n4b, 256, 0, stream>>>(row_ptr, cnt, ssrc, alps, alpd,
                                            h16, b1, outp, N, 1);

    // ---------------- layer 2 (gemm + fused alpha) ----------------
    gemm_mfma<<<gemm_blocks, 256, 0, stream>>>(outp, B2hi, B2lo, a2s, a2d,
                                               h16, alps, alpd, N, 64);
    agg_csr_kernel<<<n4b, 256, 0, stream>>>(row_ptr, cnt, ssrc, alps, alpd,
                                            h16, b2, outp, N, 0);
}